// Round 7
// baseline (241.960 us; speedup 1.0000x reference)
//
#include <hip/hip_runtime.h>
#include <hip/hip_bf16.h>

// 3-layer SplineConv (3x3, degree 2, open spline). Atomic-free, deep fusion.
// Round 25: FULL-LINE fp32 messages. Round-6 counters: tm0 (45.2us) ==
//   gtm (47.6us) despite gtm's extra 25.6MB random G-read => time is set by
//   what both share: the m_phase 64B scattered msg stores. WRITE_SIZE=56MB
//   under write-through (2x the 25.6MB buffer) proves 128B-line granularity:
//   every 64B msg store is a partial-line write => write-allocate line fill
//   (RFO) from MALL per edge (~1563/CU x ~700cyc / ~24-deep store-miss queue
//   ~= 45us). Explains equality of tm0/gtm, ILP/occupancy insensitivity
//   (r22/r23), invisible-in-FETCH fills (MALL-served), nt/agent regressions.
//   FIX: messages become 32 x fp32 = 128B = exactly one aligned line; 8
//   lanes x 16B per edge in ONE wave store instruction => coalescer emits
//   full-line stores, no RFO. Msg bytes double but stream at full BW;
//   consumers read float4/lane full lines and drop bf16 unpack VALU.
//   Agent-scope stores reverted (cost ~8us). ws use ~122MB (ws >= 268MB).
// Pipeline: init | count+rank | scan1 | scan3 | scatter(atomic-free) |
//   L1 tm0 | L2 gtm | L3 gtm | final gather.  TN=32 tiles, 18.9 KB LDS.

typedef __attribute__((ext_vector_type(8))) short short8;
typedef __attribute__((ext_vector_type(4))) float f32x4;

__device__ __forceinline__ float blo(unsigned u) {
    union { unsigned u; float f; } x; x.u = u << 16; return x.f;
}
__device__ __forceinline__ float bhi(unsigned u) {
    union { unsigned u; float f; } x; x.u = u & 0xffff0000u; return x.f;
}
__device__ __forceinline__ unsigned short f2bf(float f) {
    union { float f; unsigned u; } x; x.f = f;
    unsigned r = x.u + 0x7fffu + ((x.u >> 16) & 1u);   // RNE
    return (unsigned short)(r >> 16);
}
__device__ __forceinline__ short8 cvt8(const float* p) {
    float4 a = *(const float4*)p;
    float4 b = *(const float4*)(p + 4);
    short8 r;
    r[0] = (short)f2bf(a.x); r[1] = (short)f2bf(a.y);
    r[2] = (short)f2bf(a.z); r[3] = (short)f2bf(a.w);
    r[4] = (short)f2bf(b.x); r[5] = (short)f2bf(b.y);
    r[6] = (short)f2bf(b.z); r[7] = (short)f2bf(b.w);
    return r;
}

#define YROW 296   // sY row stride in shorts (592 B, 16B-aligned)

// ---- one edge's message slice: lane l of 8 computes channels l*4..l*4+3 ----
// 9 ds_read_b64 + ~40 FMA + ONE float4 store; 8 lanes cover a full 128B line.
__device__ __forceinline__ void m_edge(const unsigned short* sY, const float4 r,
                                       float4* __restrict__ msgOut, int n0, int l)
{
    const int srcl = __float_as_int(r.x) - n0;
    const int dp   = __float_as_int(r.y);
    const float p0 = r.z, p1 = r.w;

    const float qb[3] = {0.5f * (1.f - p0) * (1.f - p0), -p0 * p0 + p0 + 0.5f, 0.5f * p0 * p0};
    const float qa[3] = {0.5f * (1.f - p1) * (1.f - p1), -p1 * p1 + p1 + 0.5f, 0.5f * p1 * p1};

    const uint2* yb = (const uint2*)(sY + srcl * YROW) + l;   // channels l*4..+3 of kernel k at +k*8
    float s0 = 0.f, s1 = 0.f, s2 = 0.f, s3 = 0.f;
    #pragma unroll
    for (int a = 0; a < 3; ++a) {
        float z0 = 0.f, z1 = 0.f, z2 = 0.f, z3 = 0.f;
        #pragma unroll
        for (int b = 0; b < 3; ++b) {
            uint2 v = yb[(a * 3 + b) * 8];
            const float cw = qb[b];
            z0 = fmaf(cw, blo(v.x), z0); z1 = fmaf(cw, bhi(v.x), z1);
            z2 = fmaf(cw, blo(v.y), z2); z3 = fmaf(cw, bhi(v.y), z3);
        }
        s0 = fmaf(qa[a], z0, s0); s1 = fmaf(qa[a], z1, s1);
        s2 = fmaf(qa[a], z2, s2); s3 = fmaf(qa[a], z3, s3);
    }
    msgOut[(size_t)dp * 8 + l] = float4{s0, s1, s2, s3};   // full-line write, no RFO
}

// ---- M phase: 32 edge streams/block (8 lanes each), 2 streams/iter, 2-deep prefetch ----
__device__ __forceinline__ void m_phase(const unsigned short* sY,
                                        const int* __restrict__ sstart,
                                        const float4* __restrict__ erec,
                                        float4* __restrict__ msgOut,
                                        int n0, int t, int N, int E)
{
    const int e0 = sstart[n0];
    const int e1 = (n0 + 32 < N) ? sstart[n0 + 32] : E;
    const int l  = t & 7;

    int e = e0 + (t >> 3);     // 32 streams, stride 32
    if (e >= e1) return;
    float4 r0 = erec[e];
    bool  has1 = (e + 32 < e1);
    float4 r1;
    if (has1) r1 = erec[e + 32];

    while (true) {
        const int ep0 = e + 64, ep1 = e + 96;
        const bool hp0 = ep0 < e1, hp1 = ep1 < e1;
        float4 rp0, rp1;
        if (hp0) rp0 = erec[ep0];          // 2-deep prefetch
        if (hp1) rp1 = erec[ep1];

        m_edge(sY, r0, msgOut, n0, l);
        if (!has1) break;
        m_edge(sY, r1, msgOut, n0, l);

        if (!hp0) break;
        r0 = rp0; r1 = rp1; has1 = hp1; e = ep0;
    }
}

// ---- T core (TN=32): per-tile acc, written immediately (~8 live VGPRs) ----
template<int NHALF>  // 2: K=64, 1: K=32
__device__ __forceinline__ void t_core(short8 a0, short8 a1,
                                       const unsigned short* __restrict__ Wt,
                                       const float* __restrict__ bias,
                                       unsigned short* sY, float* __restrict__ aggOut,
                                       int n0, int rh, int cgp, int lc, int q, int N)
{
    const int CIN = NHALF * 32;
    #pragma unroll
    for (int j = 0; j < 10; ++j) {
        const int ti = cgp * 10 + j;
        const unsigned short* wp = Wt + ((size_t)(ti * 16 + lc)) * CIN + q * 8;
        f32x4 acc = (f32x4){0.f, 0.f, 0.f, 0.f};
        acc = __builtin_amdgcn_mfma_f32_16x16x32_bf16(a0, *(const short8*)wp, acc, 0, 0, 0);
        if (NHALF == 2)
            acc = __builtin_amdgcn_mfma_f32_16x16x32_bf16(a1, *(const short8*)(wp + 32), acc, 0, 0, 0);

        if (ti < 18) {
            #pragma unroll
            for (int r = 0; r < 4; ++r) {
                int nl = rh * 16 + q * 4 + r;
                sY[nl * YROW + ti * 16 + lc] = f2bf(acc[r]);
            }
        } else {
            int c = (ti - 18) * 16 + lc;
            float bv = bias[c];
            #pragma unroll
            for (int r = 0; r < 4; ++r) {
                int n = n0 + rh * 16 + q * 4 + r;
                if (n < N) aggOut[(size_t)n * 32 + c] = acc[r] + bv;
            }
        }
    }
}

// L1: X = x [N,64] from global
__global__ __launch_bounds__(256, 6)
void layer_tm0(const float* __restrict__ Xa,
               const unsigned short* __restrict__ Wt, const float* __restrict__ bias,
               const int* __restrict__ sstart, const float4* __restrict__ erec,
               float* __restrict__ aggOut, float4* __restrict__ msgOut, int N, int E)
{
    __shared__ __align__(16) unsigned short sY[32 * YROW];   // 18,944 B
    const int t = threadIdx.x, wv = t >> 6, lane = t & 63;
    const int lc = lane & 15, q = lane >> 4;
    const int rh = wv & 1, cgp = wv >> 1;
    const int n0 = blockIdx.x * 32;

    int na = n0 + rh * 16 + lc;
    if (na >= N) na = N - 1;
    const float* p = Xa + (size_t)na * 64 + q * 8;
    short8 a0 = cvt8(p);
    short8 a1 = cvt8(p + 32);

    t_core<2>(a0, a1, Wt, bias, sY, aggOut, n0, rh, cgp, lc, q, N);
    __syncthreads();
    m_phase(sY, sstart, erec, msgOut, n0, t, N, E);
}

// L2 (MODE 1): X = [relu(aggPrev + gather msgIn) | skip]; L3 (MODE 2): X = relu(...)
// G phase: 8 lanes/node, lane j owns channels j*4..+3; per edge 8 lanes read
// one full 128B line (float4 each); dual accumulator unroll-2.
template<int MODE>
__global__ __launch_bounds__(256, 6)
void layer_gtm(const float* __restrict__ aggPrev, const float* __restrict__ skipv,
               const unsigned short* __restrict__ Wt, const float* __restrict__ bias,
               const int* __restrict__ sstart, const int* __restrict__ dstart,
               const float4* __restrict__ erec,
               const float4* __restrict__ msgIn, float4* __restrict__ msgOut,
               float* __restrict__ aggOut, int N, int E)
{
    __shared__ __align__(16) unsigned short sY[32 * YROW];
    float* sH = (float*)sY;    // [32][36] fp32 = 4608 B; consumed before sY written
    const int t = threadIdx.x, wv = t >> 6, lane = t & 63;
    const int lc = lane & 15, q = lane >> 4;
    const int rh = wv & 1, cgp = wv >> 1;
    const int n0 = blockIdx.x * 32;

    // ---- cooperative G phase: 256 threads, 8 lanes/node ----
    {
        const int nl = t >> 3;          // node within tile (0..31)
        const int j  = t & 7;           // channel quad (4 ch)
        int n = n0 + nl;
        if (n >= N) n = N - 1;          // duplicate-gather padding rows
        float4 A = *(const float4*)(aggPrev + (size_t)n * 32 + j * 4);
        float4 C = {0.f, 0.f, 0.f, 0.f};
        const int ge0 = dstart[n] - E;
        const int ge1 = ((n + 1 < N) ? dstart[n + 1] : 2 * E) - E;
        const float4* mp = msgIn + j;
        int e = ge0;
        for (; e + 1 < ge1; e += 2) {   // 2 full-line loads in flight
            float4 v0 = mp[(size_t)e * 8];
            float4 v1 = mp[(size_t)(e + 1) * 8];
            A.x += v0.x; A.y += v0.y; A.z += v0.z; A.w += v0.w;
            C.x += v1.x; C.y += v1.y; C.z += v1.z; C.w += v1.w;
        }
        if (e < ge1) {
            float4 v = mp[(size_t)e * 8];
            A.x += v.x; A.y += v.y; A.z += v.z; A.w += v.w;
        }
        A.x += C.x; A.y += C.y; A.z += C.z; A.w += C.w;
        float4 R;
        R.x = fmaxf(A.x, 0.f); R.y = fmaxf(A.y, 0.f);
        R.z = fmaxf(A.z, 0.f); R.w = fmaxf(A.w, 0.f);
        *(float4*)(sH + nl * 36 + j * 4) = R;   // row stride 36 floats (16B-aligned)
    }
    __syncthreads();

    // every lane reads its 8 A-frag channels from sH
    const float* hp = sH + (rh * 16 + lc) * 36 + q * 8;
    union { short8 v; __hip_bfloat162 h2[4]; } pk;
    #pragma unroll
    for (int j = 0; j < 4; ++j)
        pk.h2[j] = __float22bfloat162_rn(float2{hp[2 * j], hp[2 * j + 1]});
    short8 a0 = pk.v;
    short8 a1;
    if (MODE == 1) {
        int na = n0 + rh * 16 + lc;
        if (na >= N) na = N - 1;
        a1 = cvt8(skipv + (size_t)na * 32 + q * 8);
    }
    __syncthreads();   // all sH reads done before t_core overwrites sY

    t_core<(MODE == 1) ? 2 : 1>(a0, a1, Wt, bias, sY, aggOut, n0, rh, cgp, lc, q, N);
    __syncthreads();
    m_phase(sY, sstart, erec, msgOut, n0, t, N, E);
}

// final gather: out = relu(out + sum msg rows); 32 nodes/block, 8 lanes/node
__global__ __launch_bounds__(256)
void gather_kernel(const int* __restrict__ dstart, const float4* __restrict__ msg4,
                   float* __restrict__ agg, int N, int E)
{
    const int t = threadIdx.x;
    const int n = blockIdx.x * 32 + (t >> 3);
    if (n >= N) return;
    const int j = t & 7;            // channel quad

    const int e0 = dstart[n] - E;
    const int e1 = ((n + 1 < N) ? dstart[n + 1] : 2 * E) - E;

    float4* ap = (float4*)(agg + (size_t)n * 32 + j * 4);
    float4 A = ap[0];
    float4 C = {0.f, 0.f, 0.f, 0.f};
    const float4* mp = msg4 + j;
    int e = e0;
    for (; e + 1 < e1; e += 2) {
        float4 v0 = mp[(size_t)e * 8];
        float4 v1 = mp[(size_t)(e + 1) * 8];
        A.x += v0.x; A.y += v0.y; A.z += v0.z; A.w += v0.w;
        C.x += v1.x; C.y += v1.y; C.z += v1.z; C.w += v1.w;
    }
    if (e < e1) {
        float4 v = mp[(size_t)e * 8];
        A.x += v.x; A.y += v.y; A.z += v.z; A.w += v.w;
    }
    A.x += C.x; A.y += C.y; A.z += C.z; A.w += C.w;
    A.x = fmaxf(A.x, 0.f); A.y = fmaxf(A.y, 0.f);
    A.z = fmaxf(A.z, 0.f); A.w = fmaxf(A.w, 0.f);
    ap[0] = A;
}

// ---------- prep ----------

__global__ __launch_bounds__(256)
void init_kernel(int* __restrict__ hist, int n2,
                 const float* __restrict__ W1, const float* __restrict__ root1,
                 const float* __restrict__ W2, const float* __restrict__ root2,
                 unsigned short* __restrict__ Wt1, unsigned short* __restrict__ Wt2)
{
    int i = blockIdx.x * 256 + threadIdx.x;
    if (i < n2) { hist[i] = 0; return; }
    int j = i - n2;
    if (j < 320 * 64) {
        int col = j / 64, k = j % 64;
        float v = (col < 288) ? W1[((size_t)(col >> 5) * 64 + k) * 32 + (col & 31)]
                              : root1[(size_t)k * 32 + (col - 288)];
        Wt1[j] = f2bf(v);
    } else if (j < 320 * 96) {
        int jj = j - 320 * 64;
        int col = jj / 32, k = jj % 32;
        float v = (col < 288) ? W2[((size_t)(col >> 5) * 32 + k) * 32 + (col & 31)]
                              : root2[(size_t)k * 32 + (col - 288)];
        Wt2[jj] = f2bf(v);
    }
}

__global__ __launch_bounds__(256)
void count_rank_kernel(const int* __restrict__ ei, int* __restrict__ hist,
                       uint2* __restrict__ rank, int N, int E)
{
    int e = blockIdx.x * 256 + threadIdx.x;
    if (e >= E) return;
    unsigned rs = atomicAdd((unsigned*)&hist[ei[e]], 1u);
    unsigned rd = atomicAdd((unsigned*)&hist[N + ei[E + e]], 1u);
    rank[e] = uint2{rs, rd};
}

__global__ __launch_bounds__(1024)
void scan1_kernel(int* __restrict__ hist, int* __restrict__ bsum, int n)
{
    __shared__ int s[1024];
    int tid = threadIdx.x;
    int i = blockIdx.x * 1024 + tid;
    int v = (i < n) ? hist[i] : 0;
    s[tid] = v;
    __syncthreads();
    for (int off = 1; off < 1024; off <<= 1) {
        int add = (tid >= off) ? s[tid - off] : 0;
        __syncthreads();
        s[tid] += add;
        __syncthreads();
    }
    if (i < n) hist[i] = s[tid] - v;
    if (tid == 1023) bsum[blockIdx.x] = s[1023];
}

__global__ __launch_bounds__(1024)
void scan3_kernel(int* __restrict__ hist, const int* __restrict__ bsum, int n)
{
    __shared__ int sred[128];
    int tid = threadIdx.x;
    int b = blockIdx.x;
    if (tid < 128) sred[tid] = (tid < b) ? bsum[tid] : 0;
    __syncthreads();
    for (int off = 64; off > 0; off >>= 1) {
        if (tid < off) sred[tid] += sred[tid + off];
        __syncthreads();
    }
    int pre = sred[0];
    int i = b * 1024 + tid;
    if (i < n) hist[i] += pre;
}

__global__ __launch_bounds__(256)
void scatter_plain_kernel(const int* __restrict__ ei, const float* __restrict__ pseudo,
                          const int* __restrict__ start, const uint2* __restrict__ rank,
                          float4* __restrict__ erec, int N, int E)
{
    int e = blockIdx.x * 256 + threadIdx.x;
    if (e >= E) return;
    int sv = ei[e];
    int dv = ei[E + e];
    uint2 rk = rank[e];
    int ps = start[sv] + (int)rk.x;
    int pd = start[N + dv] + (int)rk.y - E;
    float4 r;
    r.x = __int_as_float(sv);
    r.y = __int_as_float(pd);
    r.z = pseudo[2 * (size_t)e];
    r.w = pseudo[2 * (size_t)e + 1];
    erec[ps] = r;
}

extern "C" void kernel_launch(void* const* d_in, const int* in_sizes, int n_in,
                              void* d_out, int out_size, void* d_ws, size_t ws_size,
                              hipStream_t stream) {
    const float* x      = (const float*)d_in[0];
    const int*   ei     = (const int*)  d_in[1];
    const float* pseudo = (const float*)d_in[2];
    const float* skip   = (const float*)d_in[3];
    const float* W1     = (const float*)d_in[4];
    const float* root1  = (const float*)d_in[5];
    const float* b1     = (const float*)d_in[6];
    const float* W2     = (const float*)d_in[7];
    const float* root2  = (const float*)d_in[8];
    const float* b2     = (const float*)d_in[9];

    const int N = in_sizes[0] / 64;
    const int E = in_sizes[1] / 2;
    float* out = (float*)d_out;

    // ws (~122 MB): msgA[E*32 f32] msgB[E*32 f32] agg1[N*32] agg2[N*32]
    //               erec[E f4] start[2N] bsum[256] Wt1 Wt2; rank aliases msgB
    float*  msgA  = (float*)d_ws;
    float*  msgB  = msgA + (size_t)E * 32;
    float*  agg1  = msgB + (size_t)E * 32;
    float*  agg2  = agg1 + (size_t)N * 32;
    float4* erec  = (float4*)(agg2 + (size_t)N * 32);
    int*    start = (int*)(erec + E);
    int*    bsum  = start + 2 * N;
    unsigned short* Wt1 = (unsigned short*)(bsum + 256);
    unsigned short* Wt2 = Wt1 + 320 * 64;
    uint2*  rank  = (uint2*)msgB;    // prep-only, dead before msgB first written

    const dim3 blk(256);
    const int tb   = (N + 31) / 32;
    const int gb   = (N + 31) / 32;
    const int e256 = (E + 255) / 256;
    const int n2k  = (2 * N + 1023) / 1024;   // <=128 (scan3 prefix cap)
    const int itot = 2 * N + 320 * 96;
    int* dstart = start + N;

    // ---- prep (5 launches) ----
    init_kernel<<<(itot + 255) / 256, blk, 0, stream>>>(start, 2 * N, W1, root1, W2, root2, Wt1, Wt2);
    count_rank_kernel<<<e256, blk, 0, stream>>>(ei, start, rank, N, E);
    scan1_kernel<<<n2k, 1024, 0, stream>>>(start, bsum, 2 * N);
    scan3_kernel<<<n2k, 1024, 0, stream>>>(start, bsum, 2 * N);
    scatter_plain_kernel<<<e256, blk, 0, stream>>>(ei, pseudo, start, rank, erec, N, E);

    // ---- layers (4 launches) ----
    layer_tm0<<<tb, blk, 0, stream>>>(x, Wt1, b1, start, erec, agg1, (float4*)msgA, N, E);
    layer_gtm<1><<<tb, blk, 0, stream>>>(agg1, skip, Wt1, b1, start, dstart, erec,
                                         (const float4*)msgA, (float4*)msgB, agg2, N, E);
    layer_gtm<2><<<tb, blk, 0, stream>>>(agg2, nullptr, Wt2, b2, start, dstart, erec,
                                         (const float4*)msgB, (float4*)msgA, out, N, E);
    gather_kernel<<<gb, blk, 0, stream>>>(dstart, (const float4*)msgA, out, N, E);
}